// Round 6
// baseline (129.638 us; speedup 1.0000x reference)
//
#include <hip/hip_runtime.h>
#include <stdint.h>

// Sizes: h (8,1024,512) f32, s (8,128,1024)->(1024,1024) f32,
//        Wh (512,128), Ws (1024,128), b,v (128,), out (8,128,1024) f32.
//
// Identity 1: tanh(ps+ph) = 1 - 2/(Eps*Eph + 1),
//   Eps = exp2(2*log2e*ps), Eph = exp2(2*log2e*ph) precomputed in GEMM
//   epilogue (1.18M exp2 instead of 134M in the attn loop).
// Identity 2: sum_a v_a/w_a over 4 terms shares ONE rcp via rational-sum
//   pairwise merging (14 VALU + 1 rcp per 4 terms).
// This round: the 14 VALU run PACKED over the x-pair (v_pk_fma_f32 /
//   v_pk_mul_f32 via float2 ext-vectors + __builtin_elementwise_fma),
//   halving VALU issue slots: 9 -> 5.5 issue-cyc per element.
//
// Pipeline:
//   1. transpose_cast : WhT[a][c], WsT[a][d] bf16 (k-contiguous A operands)
//   2. gemm_fused     : barrier-free register MFMA GEMM; epilogue writes
//                       Eph[n][a][x], Eps[a][ny]
//   3. attn_softmax   : 512 blocks x 512 thr, 2y x 2x per thread,
//                       4-term rcp sharing, packed-f32 inner loop.

typedef float  f32x4  __attribute__((ext_vector_type(4)));
typedef float  f32x2  __attribute__((ext_vector_type(2)));
typedef __bf16 bf16x8 __attribute__((ext_vector_type(8)));

#define LOG2E     1.4426950408889634f
#define TWO_LOG2E 2.8853900817779268f
#define FMA2(a, b, c) __builtin_elementwise_fma((a), (b), (c))

// ------------------------------------------------- weight transpose + cast
__global__ void __launch_bounds__(256) transpose_cast(
    const float* __restrict__ Wh, const float* __restrict__ Ws,
    __bf16* __restrict__ WhT, __bf16* __restrict__ WsT)
{
    int bid = blockIdx.x;  // 0..7 -> Wh tiles, 8..23 -> Ws tiles
    const float* src; __bf16* dst; int K, c0;
    if (bid < 8) { src = Wh; dst = WhT; K = 512;  c0 = bid * 64; }
    else         { src = Ws; dst = WsT; K = 1024; c0 = (bid - 8) * 64; }
    __shared__ float tile[64][129];
    int t = threadIdx.x;
    for (int i = 0; i < 8192; i += 256) {
        int idx = i + t;
        int r = idx >> 7, col = idx & 127;              // 64 rows(c) x 128 cols(a)
        tile[r][col] = src[(size_t)(c0 + r) * 128 + col];
    }
    __syncthreads();
    for (int i = 0; i < 8192; i += 256) {
        int idx = i + t;
        int a = idx >> 6, cc = idx & 63;                // 128 rows(a) x 64 cols(c)
        dst[(size_t)a * K + c0 + cc] = (__bf16)tile[cc][a];
    }
}

// --------------------------------------- barrier-free register MFMA GEMM
// blocks 0..255 : Eph  (A=WhT 128x512,  B=h f32,  32 cols/block)
// blocks 256..287: Eps (A=WsT 128x1024, B=s f32,  32 cols/block, +bias)
// wave w: m-half = (w&1)*64 (4 m-tiles), col-group = (w>>1)*16.
__global__ void __launch_bounds__(256) gemm_fused(
    const __bf16* __restrict__ WhT, const __bf16* __restrict__ WsT,
    const float* __restrict__ h, const float* __restrict__ s,
    float* __restrict__ Eph, float* __restrict__ Eps,
    const float* __restrict__ bias)
{
    int bid = blockIdx.x;
    int tid = threadIdx.x, lane = tid & 63, w = tid >> 6;
    int mbase = (w & 1) * 64;
    const __bf16* A; const float* B; float* Cp; int K; bool isPs;
    int colg;
    if (bid < 256) {
        isPs = false; A = WhT; B = h; K = 512;
        colg = bid * 32 + (w >> 1) * 16;
        int n = colg >> 10, x = colg & 1023;
        Cp = Eph + (size_t)n * 131072 + x;     // + m*1024 + col in epilogue
    } else {
        isPs = true; A = WsT; B = s; K = 1024;
        colg = (bid - 256) * 32 + (w >> 1) * 16;
        Cp = Eps + colg;
    }
    int q = lane >> 4;
    const float*  Bp = B + (size_t)(colg + (lane & 15)) * K + q * 8;
    const __bf16* Ap = A + (size_t)(mbase + (lane & 15)) * K + q * 8;

    f32x4 acc[4] = {};
    float4 b0 = *(const float4*)(Bp);
    float4 b1 = *(const float4*)(Bp + 4);
    bf16x8 a_[4];
    #pragma unroll
    for (int i = 0; i < 4; ++i) a_[i] = *(const bf16x8*)(Ap + (size_t)i * 16 * K);

    for (int k0 = 0; k0 < K; k0 += 32) {
        int kn = k0 + 32; if (kn > K - 32) kn = K - 32;   // clamped (dup last)
        float4 nb0 = *(const float4*)(Bp + kn);
        float4 nb1 = *(const float4*)(Bp + kn + 4);
        bf16x8 na[4];
        #pragma unroll
        for (int i = 0; i < 4; ++i)
            na[i] = *(const bf16x8*)(Ap + (size_t)i * 16 * K + kn);
        bf16x8 bf;
        bf[0] = (__bf16)b0.x; bf[1] = (__bf16)b0.y;
        bf[2] = (__bf16)b0.z; bf[3] = (__bf16)b0.w;
        bf[4] = (__bf16)b1.x; bf[5] = (__bf16)b1.y;
        bf[6] = (__bf16)b1.z; bf[7] = (__bf16)b1.w;
        #pragma unroll
        for (int i = 0; i < 4; ++i)
            acc[i] = __builtin_amdgcn_mfma_f32_16x16x32_bf16(a_[i], bf, acc[i], 0, 0, 0);
        b0 = nb0; b1 = nb1;
        #pragma unroll
        for (int i = 0; i < 4; ++i) a_[i] = na[i];
    }

    // C/D layout: col=lane&15, row(within 16-tile)=q*4+r  (m89-verified)
    int col = lane & 15;
    #pragma unroll
    for (int i = 0; i < 4; ++i) {
        #pragma unroll
        for (int r = 0; r < 4; ++r) {
            int m = mbase + i * 16 + q * 4 + r;
            float vv = acc[i][r];
            if (isPs) vv += bias[m];
            Cp[(size_t)m * 1024 + col] =
                __builtin_amdgcn_exp2f(vv * TWO_LOG2E);
        }
    }
}

// ------------------------------------------- fused tanh-dot + softmax
// block = (n, y-pair), 512 threads; thread t owns x = {2t, 2t+1}, 2 y-rows.
// acc[y] (f32x2 over x-pair) = sum_a v_a * rcp(w_a),
//   w_a = fma(Eps_y[a], Eph[a][x], 1), 4 a-terms per rcp via rational
//   merging; all merge arithmetic packed over the x-pair (v_pk_*_f32).
__global__ void __launch_bounds__(512) attn_softmax(
    const float* __restrict__ Eph, const float* __restrict__ Eps,
    const float* __restrict__ v, float* __restrict__ out)
{
    int bid = blockIdx.x;            // 512 blocks = n(8) x yg(64)
    int n = bid >> 6, yg = bid & 63;
    int ny = n * 128 + yg * 2;       // 2 consecutive global rows
    const f32x2* ph2 = (const f32x2*)(Eph + (size_t)n * 131072);
    int t = threadIdx.x;

    __shared__ float4 pv_s[128];     // {Eps[y0][a], Eps[y1][a], v[a], 0}
    __shared__ float wred[2][8];
    __shared__ float VsumS;

    if (t < 128) {
        float2 p = *(const float2*)(Eps + (size_t)t * 1024 + ny);
        float4 pk; pk.x = p.x; pk.y = p.y; pk.z = v[t]; pk.w = 0.f;
        pv_s[t] = pk;
    }
    if (t >= 448) {                  // last wave computes Vsum (disjoint)
        int l = t - 448;
        float vv = v[l] + v[l + 64];
        for (int m = 32; m; m >>= 1) vv += __shfl_xor(vv, m);
        if (l == 0) VsumS = vv;
    }
    __syncthreads();
    float Vsum = VsumS;

    f32x2 acc0 = {0.f, 0.f}, acc1 = {0.f, 0.f};
    const f32x2 one2 = {1.f, 1.f};
    #pragma unroll 2
    for (int a = 0; a < 128; a += 4) {
        float4 q0 = pv_s[a + 0], q1 = pv_s[a + 1];
        float4 q2 = pv_s[a + 2], q3 = pv_s[a + 3];
        f32x2 p0 = ph2[(a + 0) * 512 + t];
        f32x2 p1 = ph2[(a + 1) * 512 + t];
        f32x2 p2 = ph2[(a + 2) * 512 + t];
        f32x2 p3 = ph2[(a + 3) * 512 + t];
        // 4-term rational sum, packed over the x-pair:
        // 14 pk-VALU + 2 rcp per (y, x-pair, 4 a-terms)
        auto comb2 = [&](float e0, float e1, float e2, float e3,
                         f32x2& acc) {
            f32x2 w0 = FMA2((f32x2)e0, p0, one2);
            f32x2 w1 = FMA2((f32x2)e1, p1, one2);
            f32x2 w2 = FMA2((f32x2)e2, p2, one2);
            f32x2 w3 = FMA2((f32x2)e3, p3, one2);
            f32x2 d01 = w0 * w1, d23 = w2 * w3;
            f32x2 n01 = FMA2((f32x2)q1.z, w0, (f32x2)q0.z * w1);
            f32x2 n23 = FMA2((f32x2)q3.z, w2, (f32x2)q2.z * w3);
            f32x2 dd = d01 * d23;
            f32x2 nn = FMA2(n23, d01, n01 * d23);
            f32x2 r;
            r.x = __builtin_amdgcn_rcpf(dd.x);
            r.y = __builtin_amdgcn_rcpf(dd.y);
            acc = FMA2(nn, r, acc);
        };
        comb2(q0.x, q1.x, q2.x, q3.x, acc0);   // y0
        comb2(q0.y, q1.y, q2.y, q3.y, acc1);   // y1
    }
    f32x2 e0v = FMA2((f32x2)(-2.f), acc0, (f32x2)Vsum);
    f32x2 e1v = FMA2((f32x2)(-2.f), acc1, (f32x2)Vsum);
    float e00 = e0v.x, e01 = e0v.y, e10 = e1v.x, e11 = e1v.y;

    int lane = t & 63, wv = t >> 6;
    float mx0 = fmaxf(e00, e01), mx1 = fmaxf(e10, e11);
    for (int m = 32; m; m >>= 1) {
        mx0 = fmaxf(mx0, __shfl_xor(mx0, m));
        mx1 = fmaxf(mx1, __shfl_xor(mx1, m));
    }
    if (lane == 0) { wred[0][wv] = mx0; wred[1][wv] = mx1; }
    __syncthreads();
    mx0 = wred[0][0]; mx1 = wred[1][0];
    #pragma unroll
    for (int i = 1; i < 8; ++i) {
        mx0 = fmaxf(mx0, wred[0][i]);
        mx1 = fmaxf(mx1, wred[1][i]);
    }
    __syncthreads();
    float s00 = __builtin_amdgcn_exp2f((e00 - mx0) * LOG2E);
    float s01 = __builtin_amdgcn_exp2f((e01 - mx0) * LOG2E);
    float s10 = __builtin_amdgcn_exp2f((e10 - mx1) * LOG2E);
    float s11 = __builtin_amdgcn_exp2f((e11 - mx1) * LOG2E);
    float sm0 = s00 + s01, sm1 = s10 + s11;
    for (int m = 32; m; m >>= 1) {
        sm0 += __shfl_xor(sm0, m);
        sm1 += __shfl_xor(sm1, m);
    }
    if (lane == 0) { wred[0][wv] = sm0; wred[1][wv] = sm1; }
    __syncthreads();
    sm0 = 0.f; sm1 = 0.f;
    #pragma unroll
    for (int i = 0; i < 8; ++i) { sm0 += wred[0][i]; sm1 += wred[1][i]; }
    float r0 = __builtin_amdgcn_rcpf(sm0);
    float r1 = __builtin_amdgcn_rcpf(sm1);
    float2 o0; o0.x = s00 * r0; o0.y = s01 * r0;
    float2 o1; o1.x = s10 * r1; o1.y = s11 * r1;
    ((float2*)(out + (size_t)(ny + 0) * 1024))[t] = o0;
    ((float2*)(out + (size_t)(ny + 1) * 1024))[t] = o1;
}

// ----------------------------------------------------------------- launcher
extern "C" void kernel_launch(void* const* d_in, const int* in_sizes, int n_in,
                              void* d_out, int out_size, void* d_ws, size_t ws_size,
                              hipStream_t stream) {
    const float* h  = (const float*)d_in[0];
    const float* s  = (const float*)d_in[1];
    const float* Wh = (const float*)d_in[2];
    const float* Ws = (const float*)d_in[3];
    const float* b  = (const float*)d_in[4];
    const float* v  = (const float*)d_in[5];
    float* out = (float*)d_out;

    char* ws = (char*)d_ws;
    float*  Eph = (float*)ws;                                  // 4 MB
    float*  Eps = (float*)(ws + (4u << 20));                   // 512 KB
    __bf16* WhT = (__bf16*)(ws + (4u << 20) + (512u << 10));   // 128 KB
    __bf16* WsT = WhT + (size_t)128 * 512;                     // 256 KB

    transpose_cast<<<24, 256, 0, stream>>>(Wh, Ws, WhT, WsT);
    gemm_fused<<<288, 256, 0, stream>>>(WhT, WsT, h, s, Eph, Eps, b);
    attn_softmax<<<512, 512, 0, stream>>>(Eph, Eps, v, out);
}